// Round 1
// baseline (332.713 us; speedup 1.0000x reference)
//
#include <hip/hip_runtime.h>
#include <math.h>

#define BB 16
#define NN_ 4096
#define DD 512
#define LL 64
#define SCALE 0.044194173824159216f
#define RMS_EPS 1e-6f

// ---------------- K0: all_padded[b] ----------------
__global__ __launch_bounds__(256) void k_allpad(const int* __restrict__ pmask, int* __restrict__ allpad) {
    int b = blockIdx.x;
    __shared__ int s_any_valid;
    if (threadIdx.x == 0) s_any_valid = 0;
    __syncthreads();
    int any_valid = 0;
    for (int n = threadIdx.x; n < NN_; n += 256)
        if (pmask[b * NN_ + n] == 0) any_valid = 1;
    if (any_valid) atomicOr(&s_any_valid, 1);
    __syncthreads();
    if (threadIdx.x == 0) allpad[b] = (s_any_valid == 0) ? 1 : 0;
}

// ---------------- K1: qproj = query @ Wq + bq ----------------
__global__ __launch_bounds__(256) void k_qproj(const float* __restrict__ query, const float* __restrict__ Wq,
                                               const float* __restrict__ bq, float* __restrict__ qproj) {
    int b = blockIdx.x;
    __shared__ float q[DD];
    for (int e = threadIdx.x; e < DD; e += 256) q[e] = query[b * DD + e];
    __syncthreads();
    for (int d = threadIdx.x; d < DD; d += 256) {
        float acc = bq[d];
        #pragma unroll 4
        for (int e = 0; e < DD; ++e) acc += q[e] * Wq[e * DD + d];
        qproj[b * DD + d] = acc;
    }
}

// ---------------- K2: Lk/Qk = rows @ Wk^T, sbL/sbQ = rows . bk ----------------
// blocks 0..63 -> latent rows, 64..79 -> qproj rows
__global__ __launch_bounds__(256) void k_lkqk(const float* __restrict__ latents, const float* __restrict__ qproj,
                                              const float* __restrict__ Wk, const float* __restrict__ bk,
                                              float* __restrict__ Lk, float* __restrict__ Qk,
                                              float* __restrict__ sbL, float* __restrict__ sbQ) {
    int r = blockIdx.x;
    __shared__ float row[DD];
    __shared__ float red[256];
    const float* src = (r < LL) ? (latents + (size_t)r * DD) : (qproj + (size_t)(r - LL) * DD);
    for (int d = threadIdx.x; d < DD; d += 256) row[d] = src[d];
    __syncthreads();
    // bias dot
    float p = 0.f;
    for (int d = threadIdx.x; d < DD; d += 256) p += bk[d] * row[d];
    red[threadIdx.x] = p;
    __syncthreads();
    for (int s = 128; s > 0; s >>= 1) {
        if (threadIdx.x < s) red[threadIdx.x] += red[threadIdx.x + s];
        __syncthreads();
    }
    if (threadIdx.x == 0) { if (r < LL) sbL[r] = red[0]; else sbQ[r - LL] = red[0]; }
    // Wk rows dot
    const float4* r4 = (const float4*)row;
    for (int e = threadIdx.x; e < DD; e += 256) {
        const float4* w4 = (const float4*)(Wk + (size_t)e * DD);
        float acc = 0.f;
        #pragma unroll 4
        for (int d4 = 0; d4 < DD / 4; ++d4) {
            float4 w = w4[d4], rr = r4[d4];
            acc += w.x * rr.x + w.y * rr.y + w.z * rr.z + w.w * rr.w;
        }
        if (r < LL) Lk[(size_t)r * DD + e] = acc;
        else        Qk[(size_t)(r - LL) * DD + e] = acc;
    }
}

// ---------------- K3: scores[b,l,n] = (tokens . (Lk+Qk) + sb) * scale ----------------
__global__ __launch_bounds__(256) void k_scores(const float* __restrict__ tokens,
                                                const float* __restrict__ Lk, const float* __restrict__ Qk,
                                                const float* __restrict__ sbL, const float* __restrict__ sbQ,
                                                float* __restrict__ scores) {
    const int b = blockIdx.y;
    const int n0 = blockIdx.x * 64;
    const int tid = threadIdx.x;
    const int lsub = (tid >> 4) << 2;
    const int nsub = (tid & 15) << 2;
    __shared__ float lq[64][68];
    __shared__ float tkb[64 * 64];  // rotated layout: [r][ ((g + (r>>2)) & 15)*4 + (c&3) ]
    float acc[4][4] = {{0.f, 0.f, 0.f, 0.f}};
    for (int d0 = 0; d0 < DD; d0 += 64) {
        for (int k = tid; k < 1024; k += 256) {
            const int rr = k >> 4, c4 = (k & 15) << 2;
            float4 lv = *(const float4*)&Lk[(size_t)rr * DD + d0 + c4];
            const float4 qv = *(const float4*)&Qk[(size_t)b * DD + d0 + c4];
            lv.x += qv.x; lv.y += qv.y; lv.z += qv.z; lv.w += qv.w;
            *(float4*)&lq[rr][c4] = lv;
            const int gp = ((c4 >> 2) + (rr >> 2)) & 15;
            *(float4*)&tkb[(rr << 6) + (gp << 2)] =
                *(const float4*)&tokens[(size_t)((b << 12) + n0 + rr) * DD + d0 + c4];
        }
        __syncthreads();
        #pragma unroll
        for (int d4 = 0; d4 < 16; ++d4) {
            float4 a[4], bbv[4];
            #pragma unroll
            for (int i = 0; i < 4; ++i) a[i] = *(const float4*)&lq[lsub + i][d4 << 2];
            const int rot = ((d4 + (nsub >> 2)) & 15) << 2;
            #pragma unroll
            for (int j = 0; j < 4; ++j) bbv[j] = *(const float4*)&tkb[((nsub + j) << 6) + rot];
            #pragma unroll
            for (int i = 0; i < 4; ++i) {
                #pragma unroll
                for (int j = 0; j < 4; ++j)
                    acc[i][j] += a[i].x * bbv[j].x + a[i].y * bbv[j].y + a[i].z * bbv[j].z + a[i].w * bbv[j].w;
            }
        }
        __syncthreads();
    }
    const float sq = sbQ[b];
    #pragma unroll
    for (int i = 0; i < 4; ++i) {
        const float sb = sbL[lsub + i] + sq;
        float4 v;
        v.x = (acc[i][0] + sb) * SCALE;
        v.y = (acc[i][1] + sb) * SCALE;
        v.z = (acc[i][2] + sb) * SCALE;
        v.w = (acc[i][3] + sb) * SCALE;
        *(float4*)&scores[(size_t)((b << 6) + lsub + i) * NN_ + n0 + nsub] = v;
    }
}

// ---------------- K4: masked softmax over n, in place ----------------
__global__ __launch_bounds__(256) void k_softmax(const int* __restrict__ pmask, const int* __restrict__ allpad,
                                                 float* __restrict__ scores) {
    const int row = blockIdx.x;       // b*64 + l
    const int b = row >> 6;
    const int tid = threadIdx.x;
    float* s = scores + (size_t)row * NN_;
    const int* m = pmask + (size_t)b * NN_;
    __shared__ float red[256];
    if (allpad[b]) {  // weights := 0, output gets zeroed later anyway
        for (int n = tid; n < NN_; n += 256) s[n] = 0.f;
        return;
    }
    float mx = -3.4e38f;
    for (int n = tid; n < NN_; n += 256)
        if (m[n] == 0) mx = fmaxf(mx, s[n]);
    red[tid] = mx;
    __syncthreads();
    for (int st = 128; st > 0; st >>= 1) {
        if (tid < st) red[tid] = fmaxf(red[tid], red[tid + st]);
        __syncthreads();
    }
    mx = red[0];
    __syncthreads();
    float sum = 0.f;
    for (int n = tid; n < NN_; n += 256) {
        float e = (m[n] == 0) ? expf(s[n] - mx) : 0.f;
        s[n] = e;
        sum += e;
    }
    red[tid] = sum;
    __syncthreads();
    for (int st = 128; st > 0; st >>= 1) {
        if (tid < st) red[tid] += red[tid + st];
        __syncthreads();
    }
    const float inv = 1.f / red[0];
    for (int n = tid; n < NN_; n += 256) s[n] *= inv;
}

// ---------------- K5: pooled partials: part[p][b,l,e] = sum_{n in chunk p} w[b,l,n]*tokens[b,n,e] ----------------
__global__ __launch_bounds__(256) void k_pool(const float* __restrict__ tokens, const float* __restrict__ weights,
                                              float* __restrict__ part) {
    const int e0 = blockIdx.x * 64;
    const int b = blockIdx.y;
    const int p = blockIdx.z;
    const int tid = threadIdx.x;
    const int lsub = (tid >> 4) << 2;
    const int esub = (tid & 15) << 2;
    __shared__ float wt[64][68];
    __shared__ float tk[64][68];
    float acc[4][4] = {{0.f, 0.f, 0.f, 0.f}};
    for (int it = 0; it < 16; ++it) {
        const int n0 = p * 1024 + it * 64;
        for (int k = tid; k < 1024; k += 256) {
            const int rr = k >> 4, c4 = (k & 15) << 2;
            *(float4*)&wt[rr][c4] = *(const float4*)&weights[(size_t)((b << 6) + rr) * NN_ + n0 + c4];
            *(float4*)&tk[rr][c4] = *(const float4*)&tokens[(size_t)((b << 12) + n0 + rr) * DD + e0 + c4];
        }
        __syncthreads();
        #pragma unroll
        for (int n4 = 0; n4 < 16; ++n4) {
            float4 a4[4];
            #pragma unroll
            for (int i = 0; i < 4; ++i) a4[i] = *(const float4*)&wt[lsub + i][n4 << 2];
            const float4 b0 = *(const float4*)&tk[(n4 << 2) + 0][esub];
            const float4 b1 = *(const float4*)&tk[(n4 << 2) + 1][esub];
            const float4 b2 = *(const float4*)&tk[(n4 << 2) + 2][esub];
            const float4 b3 = *(const float4*)&tk[(n4 << 2) + 3][esub];
            #pragma unroll
            for (int i = 0; i < 4; ++i) {
                const float4 av = a4[i];
                acc[i][0] += av.x * b0.x + av.y * b1.x + av.z * b2.x + av.w * b3.x;
                acc[i][1] += av.x * b0.y + av.y * b1.y + av.z * b2.y + av.w * b3.y;
                acc[i][2] += av.x * b0.z + av.y * b1.z + av.z * b2.z + av.w * b3.z;
                acc[i][3] += av.x * b0.w + av.y * b1.w + av.z * b2.w + av.w * b3.w;
            }
        }
        __syncthreads();
    }
    #pragma unroll
    for (int i = 0; i < 4; ++i) {
        float4 v = make_float4(acc[i][0], acc[i][1], acc[i][2], acc[i][3]);
        *(float4*)&part[(size_t)p * (BB * LL * DD) + (size_t)((b << 6) + lsub + i) * DD + e0 + esub] = v;
    }
}

// ---------------- K6: proj = (sum_p part) @ Wv + bv ----------------
__global__ __launch_bounds__(256) void k_proj(const float* __restrict__ part, const float* __restrict__ Wv,
                                              const float* __restrict__ bv, float* __restrict__ proj) {
    const int d0 = blockIdx.x * 64;
    const int r0 = blockIdx.y * 64;
    const int tid = threadIdx.x;
    const int rsub = (tid >> 4) << 2;
    const int dsub = (tid & 15) << 2;
    __shared__ float at[64][68];
    __shared__ float wv[64][68];
    float acc[4][4] = {{0.f, 0.f, 0.f, 0.f}};
    const size_t PSZ = (size_t)BB * LL * DD;
    for (int kc = 0; kc < 8; ++kc) {
        const int k0 = kc * 64;
        for (int k = tid; k < 1024; k += 256) {
            const int rr = k >> 4, c4 = (k & 15) << 2;
            const size_t ai = (size_t)(r0 + rr) * DD + k0 + c4;
            float4 s0 = *(const float4*)&part[ai];
            const float4 s1 = *(const float4*)&part[PSZ + ai];
            const float4 s2 = *(const float4*)&part[2 * PSZ + ai];
            const float4 s3 = *(const float4*)&part[3 * PSZ + ai];
            s0.x += s1.x + s2.x + s3.x;
            s0.y += s1.y + s2.y + s3.y;
            s0.z += s1.z + s2.z + s3.z;
            s0.w += s1.w + s2.w + s3.w;
            *(float4*)&at[rr][c4] = s0;
            *(float4*)&wv[rr][c4] = *(const float4*)&Wv[(size_t)(k0 + rr) * DD + d0 + c4];
        }
        __syncthreads();
        #pragma unroll
        for (int n4 = 0; n4 < 16; ++n4) {
            float4 a4[4];
            #pragma unroll
            for (int i = 0; i < 4; ++i) a4[i] = *(const float4*)&at[rsub + i][n4 << 2];
            const float4 b0 = *(const float4*)&wv[(n4 << 2) + 0][dsub];
            const float4 b1 = *(const float4*)&wv[(n4 << 2) + 1][dsub];
            const float4 b2 = *(const float4*)&wv[(n4 << 2) + 2][dsub];
            const float4 b3 = *(const float4*)&wv[(n4 << 2) + 3][dsub];
            #pragma unroll
            for (int i = 0; i < 4; ++i) {
                const float4 av = a4[i];
                acc[i][0] += av.x * b0.x + av.y * b1.x + av.z * b2.x + av.w * b3.x;
                acc[i][1] += av.x * b0.y + av.y * b1.y + av.z * b2.y + av.w * b3.y;
                acc[i][2] += av.x * b0.z + av.y * b1.z + av.z * b2.z + av.w * b3.z;
                acc[i][3] += av.x * b0.w + av.y * b1.w + av.z * b2.w + av.w * b3.w;
            }
        }
        __syncthreads();
    }
    #pragma unroll
    for (int i = 0; i < 4; ++i) {
        const int d = d0 + dsub;
        float4 v;
        v.x = acc[i][0] + bv[d + 0];
        v.y = acc[i][1] + bv[d + 1];
        v.z = acc[i][2] + bv[d + 2];
        v.w = acc[i][3] + bv[d + 3];
        *(float4*)&proj[(size_t)(r0 + rsub + i) * DD + d] = v;
    }
}

// ---------------- K7: RMSNorm + masks + outputs ----------------
__global__ __launch_bounds__(256) void k_rmsout(const float* __restrict__ proj, const float* __restrict__ norm_w,
                                                const int* __restrict__ allpad, float* __restrict__ out) {
    const int row = blockIdx.x;  // b*64 + l
    const int b = row >> 6;
    const int tid = threadIdx.x;
    __shared__ float red[256];
    const float* pr = proj + (size_t)row * DD;
    const float v0 = pr[tid], v1 = pr[tid + 256];
    red[tid] = v0 * v0 + v1 * v1;
    __syncthreads();
    for (int st = 128; st > 0; st >>= 1) {
        if (tid < st) red[tid] += red[tid + st];
        __syncthreads();
    }
    const float var = red[0] / (float)DD;
    const float r = 1.0f / sqrtf(var + RMS_EPS);
    const int ap = allpad[b];
    const float msk = ap ? 0.f : 1.f;
    out[(size_t)row * DD + tid]       = v0 * r * norm_w[tid] * msk;
    out[(size_t)row * DD + tid + 256] = v1 * r * norm_w[tid + 256] * msk;
    if (tid == 0) out[(size_t)BB * LL * DD + row] = ap ? 1.f : 0.f;
}

extern "C" void kernel_launch(void* const* d_in, const int* in_sizes, int n_in,
                              void* d_out, int out_size, void* d_ws, size_t ws_size,
                              hipStream_t stream) {
    const float* query   = (const float*)d_in[0];
    const float* tokens  = (const float*)d_in[1];
    const int*   pmask   = (const int*)d_in[2];
    const float* latents = (const float*)d_in[3];
    const float* Wq = (const float*)d_in[4];
    const float* bq = (const float*)d_in[5];
    const float* Wk = (const float*)d_in[6];
    const float* bk = (const float*)d_in[7];
    const float* Wv = (const float*)d_in[8];
    const float* bv = (const float*)d_in[9];
    const float* nw = (const float*)d_in[10];

    float* ws = (float*)d_ws;
    int*   allpad = (int*)ws;                 // 64 floats reserved
    float* qproj  = ws + 64;                  // 8192
    float* Lk     = ws + 8256;                // 32768
    float* Qk     = ws + 41024;               // 8192
    float* sbL    = ws + 49216;               // 64
    float* sbQ    = ws + 49280;               // 16 (+pad to 49408)
    float* scores = ws + 49408;               // 4194304
    float* part   = ws + 49408 + 4194304;     // 4*524288 = 2097152
    float* proj   = ws + 49408 + 4194304 + 2097152;  // 524288
    float* out    = (float*)d_out;

    k_allpad<<<16, 256, 0, stream>>>(pmask, allpad);
    k_qproj<<<16, 256, 0, stream>>>(query, Wq, bq, qproj);
    k_lkqk<<<80, 256, 0, stream>>>(latents, qproj, Wk, bk, Lk, Qk, sbL, sbQ);
    k_scores<<<dim3(64, 16), 256, 0, stream>>>(tokens, Lk, Qk, sbL, sbQ, scores);
    k_softmax<<<1024, 256, 0, stream>>>(pmask, allpad, scores);
    k_pool<<<dim3(8, 16, 4), 256, 0, stream>>>(tokens, scores, part);
    k_proj<<<dim3(8, 16), 256, 0, stream>>>(part, Wv, bv, proj);
    k_rmsout<<<1024, 256, 0, stream>>>(proj, nw, allpad, out);
}

// Round 2
// 247.360 us; speedup vs baseline: 1.3451x; 1.3451x over previous
//
#include <hip/hip_runtime.h>
#include <math.h>

#define BB 16
#define NN_ 4096
#define DD 512
#define LL 64
#define SCALE 0.044194173824159216f
#define RMS_EPS 1e-6f

using bf16x8 = __attribute__((ext_vector_type(8))) short;
using f32x4  = __attribute__((ext_vector_type(4))) float;

__device__ __forceinline__ unsigned short f2bf(float x) {
    union { float f; unsigned u; } v; v.f = x;
    return (unsigned short)((v.u + 0x7fffu + ((v.u >> 16) & 1u)) >> 16);
}

// ---------------- K0: all_padded[b] ----------------
__global__ __launch_bounds__(256) void k_allpad(const int* __restrict__ pmask, int* __restrict__ allpad) {
    int b = blockIdx.x;
    __shared__ int s_any_valid;
    if (threadIdx.x == 0) s_any_valid = 0;
    __syncthreads();
    int any_valid = 0;
    for (int n = threadIdx.x; n < NN_; n += 256)
        if (pmask[b * NN_ + n] == 0) any_valid = 1;
    if (any_valid) atomicOr(&s_any_valid, 1);
    __syncthreads();
    if (threadIdx.x == 0) allpad[b] = (s_any_valid == 0) ? 1 : 0;
}

// ---------------- K1: qproj = query @ Wq + bq ----------------
__global__ __launch_bounds__(256) void k_qproj(const float* __restrict__ query, const float* __restrict__ Wq,
                                               const float* __restrict__ bq, float* __restrict__ qproj) {
    int b = blockIdx.x;
    __shared__ float q[DD];
    for (int e = threadIdx.x; e < DD; e += 256) q[e] = query[b * DD + e];
    __syncthreads();
    for (int d = threadIdx.x; d < DD; d += 256) {
        float acc = bq[d];
        #pragma unroll 4
        for (int e = 0; e < DD; ++e) acc += q[e] * Wq[e * DD + d];
        qproj[b * DD + d] = acc;
    }
}

// ---------------- K2: Lk/Qk = rows @ Wk^T, sbL/sbQ = rows . bk ----------------
__global__ __launch_bounds__(256) void k_lkqk(const float* __restrict__ latents, const float* __restrict__ qproj,
                                              const float* __restrict__ Wk, const float* __restrict__ bk,
                                              float* __restrict__ Lk, float* __restrict__ Qk,
                                              float* __restrict__ sbL, float* __restrict__ sbQ) {
    int r = blockIdx.x;
    __shared__ float row[DD];
    __shared__ float red[256];
    const float* src = (r < LL) ? (latents + (size_t)r * DD) : (qproj + (size_t)(r - LL) * DD);
    for (int d = threadIdx.x; d < DD; d += 256) row[d] = src[d];
    __syncthreads();
    float p = 0.f;
    for (int d = threadIdx.x; d < DD; d += 256) p += bk[d] * row[d];
    red[threadIdx.x] = p;
    __syncthreads();
    for (int s = 128; s > 0; s >>= 1) {
        if (threadIdx.x < s) red[threadIdx.x] += red[threadIdx.x + s];
        __syncthreads();
    }
    if (threadIdx.x == 0) { if (r < LL) sbL[r] = red[0]; else sbQ[r - LL] = red[0]; }
    const float4* r4 = (const float4*)row;
    for (int e = threadIdx.x; e < DD; e += 256) {
        const float4* w4 = (const float4*)(Wk + (size_t)e * DD);
        float acc = 0.f;
        #pragma unroll 4
        for (int d4 = 0; d4 < DD / 4; ++d4) {
            float4 w = w4[d4], rr = r4[d4];
            acc += w.x * rr.x + w.y * rr.y + w.z * rr.z + w.w * rr.w;
        }
        if (r < LL) Lk[(size_t)r * DD + e] = acc;
        else        Qk[(size_t)(r - LL) * DD + e] = acc;
    }
}

// ---------------- K3: scores via MFMA bf16 ----------------
// block: 64 L x 128 N tile, 4 waves (each 64L x 32N), K-loop over D=512 in BK=64
__global__ __launch_bounds__(256) void k_scores_mfma(const float* __restrict__ tokens,
                                                     const float* __restrict__ Lk, const float* __restrict__ Qk,
                                                     const float* __restrict__ sbL, const float* __restrict__ sbQ,
                                                     float* __restrict__ scores) {
    const int b = blockIdx.y;
    const int n0 = blockIdx.x << 7;
    const int tid = threadIdx.x;
    const int lane = tid & 63, wv = tid >> 6;
    __shared__ unsigned short sA[64][72];    // LQ tile [l][k]
    __shared__ unsigned short sB[128][72];   // token tile [n][k]
    f32x4 acc[4][2];
    #pragma unroll
    for (int m = 0; m < 4; ++m)
        #pragma unroll
        for (int n = 0; n < 2; ++n)
            acc[m][n] = (f32x4){0.f, 0.f, 0.f, 0.f};
    const int r = lane & 15, kl = lane >> 4;

    for (int k0 = 0; k0 < DD; k0 += 64) {
        // stage A: 64x64 LQ = Lk + Qk[b], 4 float4/thread
        #pragma unroll
        for (int s = 0; s < 4; ++s) {
            const int idx = tid + (s << 8);
            const int row = idx >> 4, c4 = (idx & 15) << 2;
            const float4 lv = *(const float4*)&Lk[(size_t)row * DD + k0 + c4];
            const float4 qv = *(const float4*)&Qk[(size_t)b * DD + k0 + c4];
            ushort4 o;
            o.x = f2bf(lv.x + qv.x); o.y = f2bf(lv.y + qv.y);
            o.z = f2bf(lv.z + qv.z); o.w = f2bf(lv.w + qv.w);
            *(ushort4*)&sA[row][c4] = o;
        }
        // stage B: 128x64 tokens, 8 float4/thread
        #pragma unroll
        for (int s = 0; s < 8; ++s) {
            const int idx = tid + (s << 8);
            const int row = idx >> 4, c4 = (idx & 15) << 2;
            const float4 tv = *(const float4*)&tokens[(size_t)((b << 12) + n0 + row) * DD + k0 + c4];
            ushort4 o;
            o.x = f2bf(tv.x); o.y = f2bf(tv.y); o.z = f2bf(tv.z); o.w = f2bf(tv.w);
            *(ushort4*)&sB[row][c4] = o;
        }
        __syncthreads();
        #pragma unroll
        for (int kk = 0; kk < 64; kk += 32) {
            bf16x8 af[4], bfr[2];
            #pragma unroll
            for (int m = 0; m < 4; ++m)
                af[m] = *(const bf16x8*)&sA[(m << 4) + r][kk + (kl << 3)];
            #pragma unroll
            for (int n = 0; n < 2; ++n)
                bfr[n] = *(const bf16x8*)&sB[(wv << 5) + (n << 4) + r][kk + (kl << 3)];
            #pragma unroll
            for (int m = 0; m < 4; ++m)
                #pragma unroll
                for (int n = 0; n < 2; ++n)
                    acc[m][n] = __builtin_amdgcn_mfma_f32_16x16x32_bf16(af[m], bfr[n], acc[m][n], 0, 0, 0);
        }
        __syncthreads();
    }
    const float sq = sbQ[b];
    const int col = lane & 15, rb = (lane >> 4) << 2;
    #pragma unroll
    for (int m = 0; m < 4; ++m) {
        #pragma unroll
        for (int n = 0; n < 2; ++n) {
            #pragma unroll
            for (int q = 0; q < 4; ++q) {
                const int l = (m << 4) + rb + q;
                scores[(size_t)((b << 6) + l) * NN_ + n0 + (wv << 5) + (n << 4) + col] =
                    (acc[m][n][q] + sbL[l] + sq) * SCALE;
            }
        }
    }
}

// ---------------- K4: masked softmax over n, in place ----------------
__global__ __launch_bounds__(256) void k_softmax(const int* __restrict__ pmask, const int* __restrict__ allpad,
                                                 float* __restrict__ scores) {
    const int row = blockIdx.x;       // b*64 + l
    const int b = row >> 6;
    const int tid = threadIdx.x;
    float* s = scores + (size_t)row * NN_;
    const int* m = pmask + (size_t)b * NN_;
    __shared__ float red[256];
    if (allpad[b]) {
        for (int n = tid; n < NN_; n += 256) s[n] = 0.f;
        return;
    }
    float mx = -3.4e38f;
    for (int n = tid; n < NN_; n += 256)
        if (m[n] == 0) mx = fmaxf(mx, s[n]);
    red[tid] = mx;
    __syncthreads();
    for (int st = 128; st > 0; st >>= 1) {
        if (tid < st) red[tid] = fmaxf(red[tid], red[tid + st]);
        __syncthreads();
    }
    mx = red[0];
    __syncthreads();
    float sum = 0.f;
    for (int n = tid; n < NN_; n += 256) {
        float e = (m[n] == 0) ? expf(s[n] - mx) : 0.f;
        s[n] = e;
        sum += e;
    }
    red[tid] = sum;
    __syncthreads();
    for (int st = 128; st > 0; st >>= 1) {
        if (tid < st) red[tid] += red[tid + st];
        __syncthreads();
    }
    const float inv = 1.f / red[0];
    for (int n = tid; n < NN_; n += 256) s[n] *= inv;
}

// ---------------- K5: pool via MFMA bf16 ----------------
// grid (eb=4, b=16, z=4); block: 64 L x 128 E tile, reduction over 1024 tokens (z-chunk)
__global__ __launch_bounds__(256) void k_pool_mfma(const float* __restrict__ tokens,
                                                   const float* __restrict__ weights,
                                                   float* __restrict__ part) {
    const int e0 = blockIdx.x << 7;
    const int b  = blockIdx.y;
    const int z  = blockIdx.z;
    const int tid = threadIdx.x;
    const int lane = tid & 63, wv = tid >> 6;
    __shared__ unsigned short sW[64][72];    // weights tile [l][k=n]
    __shared__ int sT[128][36];              // tokens transposed [e][k-word], XOR swizzled
    f32x4 acc[4][2];
    #pragma unroll
    for (int m = 0; m < 4; ++m)
        #pragma unroll
        for (int n = 0; n < 2; ++n)
            acc[m][n] = (f32x4){0.f, 0.f, 0.f, 0.f};
    const int r = lane & 15, kl = lane >> 4;

    for (int ks = 0; ks < 16; ++ks) {
        const int n0 = (z << 10) + (ks << 6);
        // stage W: 64l x 64n of f32 weights -> bf16
        #pragma unroll
        for (int s = 0; s < 4; ++s) {
            const int idx = tid + (s << 8);
            const int row = idx >> 4, c4 = (idx & 15) << 2;
            const float4 w = *(const float4*)&weights[(size_t)((b << 6) + row) * NN_ + n0 + c4];
            ushort4 o;
            o.x = f2bf(w.x); o.y = f2bf(w.y); o.z = f2bf(w.z); o.w = f2bf(w.w);
            *(ushort4*)&sW[row][c4] = o;
        }
        // stage T transposed: 64n x 128e -> sT[e][n], 4 units/thread (2 tokens x 4 e each)
        #pragma unroll
        for (int s = 0; s < 4; ++s) {
            const int u = tid + (s << 8);       // 0..1023
            const int n2 = u >> 5;              // token pair 0..31
            const int e4 = (u & 31) << 2;       // e offset 0..124
            const float* p0 = &tokens[(size_t)((b << 12) + n0 + (n2 << 1)) * DD + e0 + e4];
            const float4 a = *(const float4*)p0;
            const float4 c = *(const float4*)(p0 + DD);
            const float* ap = (const float*)&a;
            const float* cp = (const float*)&c;
            #pragma unroll
            for (int j = 0; j < 4; ++j) {
                const int e = e4 + j;
                const int phys = n2 ^ ((((e >> 2) & 7)) << 2);
                sT[e][phys] = (int)((unsigned)f2bf(ap[j]) | ((unsigned)f2bf(cp[j]) << 16));
            }
        }
        __syncthreads();
        #pragma unroll
        for (int kk = 0; kk < 64; kk += 32) {
            bf16x8 af[4], bfr[2];
            #pragma unroll
            for (int m = 0; m < 4; ++m)
                af[m] = *(const bf16x8*)&sW[(m << 4) + r][kk + (kl << 3)];
            #pragma unroll
            for (int n = 0; n < 2; ++n) {
                const int e = (wv << 5) + (n << 4) + r;
                const int g = (kk >> 1) + (kl << 2);
                const int phys = g ^ ((((e >> 2) & 7)) << 2);
                bfr[n] = *(const bf16x8*)&sT[e][phys];
            }
            #pragma unroll
            for (int m = 0; m < 4; ++m)
                #pragma unroll
                for (int n = 0; n < 2; ++n)
                    acc[m][n] = __builtin_amdgcn_mfma_f32_16x16x32_bf16(af[m], bfr[n], acc[m][n], 0, 0, 0);
        }
        __syncthreads();
    }
    const int col = lane & 15, rb = (lane >> 4) << 2;
    #pragma unroll
    for (int m = 0; m < 4; ++m) {
        #pragma unroll
        for (int n = 0; n < 2; ++n) {
            #pragma unroll
            for (int q = 0; q < 4; ++q) {
                const int l = (m << 4) + rb + q;
                const int e = e0 + (wv << 5) + (n << 4) + col;
                part[(size_t)z * (BB * LL * DD) + (size_t)((b << 6) + l) * DD + e] = acc[m][n][q];
            }
        }
    }
}

// ---------------- K6: proj = (sum_p part) @ Wv + bv ----------------
__global__ __launch_bounds__(256) void k_proj(const float* __restrict__ part, const float* __restrict__ Wv,
                                              const float* __restrict__ bv, float* __restrict__ proj) {
    const int d0 = blockIdx.x * 64;
    const int r0 = blockIdx.y * 64;
    const int tid = threadIdx.x;
    const int rsub = (tid >> 4) << 2;
    const int dsub = (tid & 15) << 2;
    __shared__ float at[64][68];
    __shared__ float wv[64][68];
    float acc[4][4] = {{0.f, 0.f, 0.f, 0.f}};
    const size_t PSZ = (size_t)BB * LL * DD;
    for (int kc = 0; kc < 8; ++kc) {
        const int k0 = kc * 64;
        for (int k = tid; k < 1024; k += 256) {
            const int rr = k >> 4, c4 = (k & 15) << 2;
            const size_t ai = (size_t)(r0 + rr) * DD + k0 + c4;
            float4 s0 = *(const float4*)&part[ai];
            const float4 s1 = *(const float4*)&part[PSZ + ai];
            const float4 s2 = *(const float4*)&part[2 * PSZ + ai];
            const float4 s3 = *(const float4*)&part[3 * PSZ + ai];
            s0.x += s1.x + s2.x + s3.x;
            s0.y += s1.y + s2.y + s3.y;
            s0.z += s1.z + s2.z + s3.z;
            s0.w += s1.w + s2.w + s3.w;
            *(float4*)&at[rr][c4] = s0;
            *(float4*)&wv[rr][c4] = *(const float4*)&Wv[(size_t)(k0 + rr) * DD + d0 + c4];
        }
        __syncthreads();
        #pragma unroll
        for (int n4 = 0; n4 < 16; ++n4) {
            float4 a4[4];
            #pragma unroll
            for (int i = 0; i < 4; ++i) a4[i] = *(const float4*)&at[rsub + i][n4 << 2];
            const float4 b0 = *(const float4*)&wv[(n4 << 2) + 0][dsub];
            const float4 b1 = *(const float4*)&wv[(n4 << 2) + 1][dsub];
            const float4 b2 = *(const float4*)&wv[(n4 << 2) + 2][dsub];
            const float4 b3 = *(const float4*)&wv[(n4 << 2) + 3][dsub];
            #pragma unroll
            for (int i = 0; i < 4; ++i) {
                const float4 av = a4[i];
                acc[i][0] += av.x * b0.x + av.y * b1.x + av.z * b2.x + av.w * b3.x;
                acc[i][1] += av.x * b0.y + av.y * b1.y + av.z * b2.y + av.w * b3.y;
                acc[i][2] += av.x * b0.z + av.y * b1.z + av.z * b2.z + av.w * b3.z;
                acc[i][3] += av.x * b0.w + av.y * b1.w + av.z * b2.w + av.w * b3.w;
            }
        }
        __syncthreads();
    }
    #pragma unroll
    for (int i = 0; i < 4; ++i) {
        const int d = d0 + dsub;
        float4 v;
        v.x = acc[i][0] + bv[d + 0];
        v.y = acc[i][1] + bv[d + 1];
        v.z = acc[i][2] + bv[d + 2];
        v.w = acc[i][3] + bv[d + 3];
        *(float4*)&proj[(size_t)(r0 + rsub + i) * DD + d] = v;
    }
}

// ---------------- K7: RMSNorm + masks + outputs ----------------
__global__ __launch_bounds__(256) void k_rmsout(const float* __restrict__ proj, const float* __restrict__ norm_w,
                                                const int* __restrict__ allpad, float* __restrict__ out) {
    const int row = blockIdx.x;  // b*64 + l
    const int b = row >> 6;
    const int tid = threadIdx.x;
    __shared__ float red[256];
    const float* pr = proj + (size_t)row * DD;
    const float v0 = pr[tid], v1 = pr[tid + 256];
    red[tid] = v0 * v0 + v1 * v1;
    __syncthreads();
    for (int st = 128; st > 0; st >>= 1) {
        if (tid < st) red[tid] += red[tid + st];
        __syncthreads();
    }
    const float var = red[0] / (float)DD;
    const float r = 1.0f / sqrtf(var + RMS_EPS);
    const int ap = allpad[b];
    const float msk = ap ? 0.f : 1.f;
    out[(size_t)row * DD + tid]       = v0 * r * norm_w[tid] * msk;
    out[(size_t)row * DD + tid + 256] = v1 * r * norm_w[tid + 256] * msk;
    if (tid == 0) out[(size_t)BB * LL * DD + row] = ap ? 1.f : 0.f;
}

extern "C" void kernel_launch(void* const* d_in, const int* in_sizes, int n_in,
                              void* d_out, int out_size, void* d_ws, size_t ws_size,
                              hipStream_t stream) {
    const float* query   = (const float*)d_in[0];
    const float* tokens  = (const float*)d_in[1];
    const int*   pmask   = (const int*)d_in[2];
    const float* latents = (const float*)d_in[3];
    const float* Wq = (const float*)d_in[4];
    const float* bq = (const float*)d_in[5];
    const float* Wk = (const float*)d_in[6];
    const float* bk = (const float*)d_in[7];
    const float* Wv = (const float*)d_in[8];
    const float* bv = (const float*)d_in[9];
    const float* nw = (const float*)d_in[10];

    float* ws = (float*)d_ws;
    int*   allpad = (int*)ws;                 // 64 floats reserved
    float* qproj  = ws + 64;                  // 8192
    float* Lk     = ws + 8256;                // 32768
    float* Qk     = ws + 41024;               // 8192
    float* sbL    = ws + 49216;               // 64
    float* sbQ    = ws + 49280;               // pad to 49408
    float* scores = ws + 49408;               // 4194304 (f32 scores -> weights in place)
    float* part   = ws + 49408 + 4194304;     // 4*524288 = 2097152
    float* proj   = ws + 49408 + 4194304 + 2097152;  // 524288
    float* out    = (float*)d_out;

    k_allpad<<<16, 256, 0, stream>>>(pmask, allpad);
    k_qproj<<<16, 256, 0, stream>>>(query, Wq, bq, qproj);
    k_lkqk<<<80, 256, 0, stream>>>(latents, qproj, Wk, bk, Lk, Qk, sbL, sbQ);
    k_scores_mfma<<<dim3(32, 16), 256, 0, stream>>>(tokens, Lk, Qk, sbL, sbQ, scores);
    k_softmax<<<1024, 256, 0, stream>>>(pmask, allpad, scores);
    k_pool_mfma<<<dim3(4, 16, 4), 256, 0, stream>>>(tokens, scores, part);
    k_proj<<<dim3(8, 16), 256, 0, stream>>>(part, Wv, bv, proj);
    k_rmsout<<<1024, 256, 0, stream>>>(proj, nw, allpad, out);
}

// Round 3
// 162.832 us; speedup vs baseline: 2.0433x; 1.5191x over previous
//
#include <hip/hip_runtime.h>
#include <math.h>

#define BB 16
#define NN_ 4096
#define DD 512
#define LL 64
#define SCALE 0.044194173824159216f
#define RMS_EPS 1e-6f

using bf16x8 = __attribute__((ext_vector_type(8))) short;
using f32x4  = __attribute__((ext_vector_type(4))) float;

__device__ __forceinline__ unsigned short f2bf(float x) {
    union { float f; unsigned u; } v; v.f = x;
    return (unsigned short)((v.u + 0x7fffu + ((v.u >> 16) & 1u)) >> 16);
}

// ---------------- K0: all_padded[b] ----------------
__global__ __launch_bounds__(256) void k_allpad(const int* __restrict__ pmask, int* __restrict__ allpad) {
    int b = blockIdx.x;
    __shared__ int s_any_valid;
    if (threadIdx.x == 0) s_any_valid = 0;
    __syncthreads();
    int any_valid = 0;
    for (int n = threadIdx.x; n < NN_; n += 256)
        if (pmask[b * NN_ + n] == 0) any_valid = 1;
    if (any_valid) atomicOr(&s_any_valid, 1);
    __syncthreads();
    if (threadIdx.x == 0) allpad[b] = (s_any_valid == 0) ? 1 : 0;
}

// ---------------- K1: qproj = query @ Wq + bq ----------------
// grid (8 dblk, 16 b); 4 waves split the e-reduction, lanes = consecutive d (coalesced)
__global__ __launch_bounds__(256) void k_qproj(const float* __restrict__ query, const float* __restrict__ Wq,
                                               const float* __restrict__ bq, float* __restrict__ qproj) {
    const int b = blockIdx.y;
    const int dl = threadIdx.x & 63;
    const int d = (blockIdx.x << 6) + dl;
    const int wv = threadIdx.x >> 6;
    __shared__ float q[DD];
    __shared__ float red[4][64];
    for (int e = threadIdx.x; e < DD; e += 256) q[e] = query[b * DD + e];
    __syncthreads();
    float acc = 0.f;
    #pragma unroll 8
    for (int i = 0; i < 128; ++i) {
        const int e = (wv << 7) + i;
        acc += q[e] * Wq[(size_t)e * DD + d];
    }
    red[wv][dl] = acc;
    __syncthreads();
    if (threadIdx.x < 64) {
        const int dd = (blockIdx.x << 6) + threadIdx.x;
        qproj[(size_t)b * DD + dd] = red[0][threadIdx.x] + red[1][threadIdx.x] +
                                     red[2][threadIdx.x] + red[3][threadIdx.x] + bq[dd];
    }
}

// ---------------- K2: Lk/Qk = rows @ Wk^T, sbL/sbQ = rows . bk ----------------
// grid (8 eblk, 80 rows); 4 threads per output e, interleaved float4 reads + shfl reduce
__global__ __launch_bounds__(256) void k_lkqk(const float* __restrict__ latents, const float* __restrict__ qproj,
                                              const float* __restrict__ Wk, const float* __restrict__ bk,
                                              float* __restrict__ Lk, float* __restrict__ Qk,
                                              float* __restrict__ sbL, float* __restrict__ sbQ) {
    const int r = blockIdx.y;
    const int e0 = blockIdx.x << 6;
    const int tid = threadIdx.x;
    __shared__ float row[DD];
    const float* src = (r < LL) ? (latents + (size_t)r * DD) : (qproj + (size_t)(r - LL) * DD);
    for (int dd = tid; dd < DD; dd += 256) row[dd] = src[dd];
    __syncthreads();
    const int e = e0 + (tid >> 2);
    const int part = tid & 3;
    const float4* w4 = (const float4*)(Wk + (size_t)e * DD);
    const float4* r4 = (const float4*)row;
    float acc = 0.f;
    #pragma unroll 8
    for (int j = 0; j < 32; ++j) {
        const int d4 = part + (j << 2);
        const float4 w = w4[d4], rr = r4[d4];
        acc += w.x * rr.x + w.y * rr.y + w.z * rr.z + w.w * rr.w;
    }
    acc += __shfl_xor(acc, 1);
    acc += __shfl_xor(acc, 2);
    if (part == 0) {
        if (r < LL) Lk[(size_t)r * DD + e] = acc;
        else        Qk[(size_t)(r - LL) * DD + e] = acc;
    }
    if (blockIdx.x == 0 && tid < 64) {
        float p = 0.f;
        #pragma unroll
        for (int dd = tid; dd < DD; dd += 64) p += bk[dd] * row[dd];
        #pragma unroll
        for (int off = 32; off > 0; off >>= 1) p += __shfl_xor(p, off);
        if (tid == 0) { if (r < LL) sbL[r] = p; else sbQ[r - LL] = p; }
    }
}

// ---------------- K3: scores via MFMA bf16 ----------------
// block: 64 L x 128 N tile, 4 waves (each 64L x 32N), K-loop over D=512 in BK=64
__global__ __launch_bounds__(256) void k_scores_mfma(const float* __restrict__ tokens,
                                                     const float* __restrict__ Lk, const float* __restrict__ Qk,
                                                     const float* __restrict__ sbL, const float* __restrict__ sbQ,
                                                     float* __restrict__ scores) {
    const int b = blockIdx.y;
    const int n0 = blockIdx.x << 7;
    const int tid = threadIdx.x;
    const int lane = tid & 63, wv = tid >> 6;
    __shared__ unsigned short sA[64][72];    // LQ tile [l][k]
    __shared__ unsigned short sB[128][72];   // token tile [n][k]
    f32x4 acc[4][2];
    #pragma unroll
    for (int m = 0; m < 4; ++m)
        #pragma unroll
        for (int n = 0; n < 2; ++n)
            acc[m][n] = (f32x4){0.f, 0.f, 0.f, 0.f};
    const int r = lane & 15, kl = lane >> 4;

    for (int k0 = 0; k0 < DD; k0 += 64) {
        #pragma unroll
        for (int s = 0; s < 4; ++s) {
            const int idx = tid + (s << 8);
            const int row = idx >> 4, c4 = (idx & 15) << 2;
            const float4 lv = *(const float4*)&Lk[(size_t)row * DD + k0 + c4];
            const float4 qv = *(const float4*)&Qk[(size_t)b * DD + k0 + c4];
            ushort4 o;
            o.x = f2bf(lv.x + qv.x); o.y = f2bf(lv.y + qv.y);
            o.z = f2bf(lv.z + qv.z); o.w = f2bf(lv.w + qv.w);
            *(ushort4*)&sA[row][c4] = o;
        }
        #pragma unroll
        for (int s = 0; s < 8; ++s) {
            const int idx = tid + (s << 8);
            const int row = idx >> 4, c4 = (idx & 15) << 2;
            const float4 tv = *(const float4*)&tokens[(size_t)((b << 12) + n0 + row) * DD + k0 + c4];
            ushort4 o;
            o.x = f2bf(tv.x); o.y = f2bf(tv.y); o.z = f2bf(tv.z); o.w = f2bf(tv.w);
            *(ushort4*)&sB[row][c4] = o;
        }
        __syncthreads();
        #pragma unroll
        for (int kk = 0; kk < 64; kk += 32) {
            bf16x8 af[4], bfr[2];
            #pragma unroll
            for (int m = 0; m < 4; ++m)
                af[m] = *(const bf16x8*)&sA[(m << 4) + r][kk + (kl << 3)];
            #pragma unroll
            for (int n = 0; n < 2; ++n)
                bfr[n] = *(const bf16x8*)&sB[(wv << 5) + (n << 4) + r][kk + (kl << 3)];
            #pragma unroll
            for (int m = 0; m < 4; ++m)
                #pragma unroll
                for (int n = 0; n < 2; ++n)
                    acc[m][n] = __builtin_amdgcn_mfma_f32_16x16x32_bf16(af[m], bfr[n], acc[m][n], 0, 0, 0);
        }
        __syncthreads();
    }
    const float sq = sbQ[b];
    const int col = lane & 15, rb = (lane >> 4) << 2;
    #pragma unroll
    for (int m = 0; m < 4; ++m) {
        #pragma unroll
        for (int n = 0; n < 2; ++n) {
            #pragma unroll
            for (int q = 0; q < 4; ++q) {
                const int l = (m << 4) + rb + q;
                scores[(size_t)((b << 6) + l) * NN_ + n0 + (wv << 5) + (n << 4) + col] =
                    (acc[m][n][q] + sbL[l] + sq) * SCALE;
            }
        }
    }
}

// ---------------- K4: masked softmax over n, in place ----------------
__global__ __launch_bounds__(256) void k_softmax(const int* __restrict__ pmask, const int* __restrict__ allpad,
                                                 float* __restrict__ scores) {
    const int row = blockIdx.x;       // b*64 + l
    const int b = row >> 6;
    const int tid = threadIdx.x;
    float* s = scores + (size_t)row * NN_;
    const int* m = pmask + (size_t)b * NN_;
    __shared__ float red[256];
    if (allpad[b]) {
        for (int n = tid; n < NN_; n += 256) s[n] = 0.f;
        return;
    }
    float mx = -3.4e38f;
    for (int n = tid; n < NN_; n += 256)
        if (m[n] == 0) mx = fmaxf(mx, s[n]);
    red[tid] = mx;
    __syncthreads();
    for (int st = 128; st > 0; st >>= 1) {
        if (tid < st) red[tid] = fmaxf(red[tid], red[tid + st]);
        __syncthreads();
    }
    mx = red[0];
    __syncthreads();
    float sum = 0.f;
    for (int n = tid; n < NN_; n += 256) {
        float e = (m[n] == 0) ? expf(s[n] - mx) : 0.f;
        s[n] = e;
        sum += e;
    }
    red[tid] = sum;
    __syncthreads();
    for (int st = 128; st > 0; st >>= 1) {
        if (tid < st) red[tid] += red[tid + st];
        __syncthreads();
    }
    const float inv = 1.f / red[0];
    for (int n = tid; n < NN_; n += 256) s[n] *= inv;
}

// ---------------- K5: pool via MFMA bf16 ----------------
__global__ __launch_bounds__(256) void k_pool_mfma(const float* __restrict__ tokens,
                                                   const float* __restrict__ weights,
                                                   float* __restrict__ part) {
    const int e0 = blockIdx.x << 7;
    const int b  = blockIdx.y;
    const int z  = blockIdx.z;
    const int tid = threadIdx.x;
    const int lane = tid & 63, wv = tid >> 6;
    __shared__ unsigned short sW[64][72];    // weights tile [l][k=n]
    __shared__ int sT[128][36];              // tokens transposed [e][k-word], XOR swizzled
    f32x4 acc[4][2];
    #pragma unroll
    for (int m = 0; m < 4; ++m)
        #pragma unroll
        for (int n = 0; n < 2; ++n)
            acc[m][n] = (f32x4){0.f, 0.f, 0.f, 0.f};
    const int r = lane & 15, kl = lane >> 4;

    for (int ks = 0; ks < 16; ++ks) {
        const int n0 = (z << 10) + (ks << 6);
        #pragma unroll
        for (int s = 0; s < 4; ++s) {
            const int idx = tid + (s << 8);
            const int row = idx >> 4, c4 = (idx & 15) << 2;
            const float4 w = *(const float4*)&weights[(size_t)((b << 6) + row) * NN_ + n0 + c4];
            ushort4 o;
            o.x = f2bf(w.x); o.y = f2bf(w.y); o.z = f2bf(w.z); o.w = f2bf(w.w);
            *(ushort4*)&sW[row][c4] = o;
        }
        #pragma unroll
        for (int s = 0; s < 4; ++s) {
            const int u = tid + (s << 8);       // 0..1023
            const int n2 = u >> 5;              // token pair 0..31
            const int e4 = (u & 31) << 2;       // e offset 0..124
            const float* p0 = &tokens[(size_t)((b << 12) + n0 + (n2 << 1)) * DD + e0 + e4];
            const float4 a = *(const float4*)p0;
            const float4 c = *(const float4*)(p0 + DD);
            const float* ap = (const float*)&a;
            const float* cp = (const float*)&c;
            #pragma unroll
            for (int j = 0; j < 4; ++j) {
                const int e = e4 + j;
                const int phys = n2 ^ ((((e >> 2) & 7)) << 2);
                sT[e][phys] = (int)((unsigned)f2bf(ap[j]) | ((unsigned)f2bf(cp[j]) << 16));
            }
        }
        __syncthreads();
        #pragma unroll
        for (int kk = 0; kk < 64; kk += 32) {
            bf16x8 af[4], bfr[2];
            #pragma unroll
            for (int m = 0; m < 4; ++m)
                af[m] = *(const bf16x8*)&sW[(m << 4) + r][kk + (kl << 3)];
            #pragma unroll
            for (int n = 0; n < 2; ++n) {
                const int e = (wv << 5) + (n << 4) + r;
                const int g = (kk >> 1) + (kl << 2);
                const int phys = g ^ ((((e >> 2) & 7)) << 2);
                bfr[n] = *(const bf16x8*)&sT[e][phys];
            }
            #pragma unroll
            for (int m = 0; m < 4; ++m)
                #pragma unroll
                for (int n = 0; n < 2; ++n)
                    acc[m][n] = __builtin_amdgcn_mfma_f32_16x16x32_bf16(af[m], bfr[n], acc[m][n], 0, 0, 0);
        }
        __syncthreads();
    }
    const int col = lane & 15, rb = (lane >> 4) << 2;
    #pragma unroll
    for (int m = 0; m < 4; ++m) {
        #pragma unroll
        for (int n = 0; n < 2; ++n) {
            #pragma unroll
            for (int q = 0; q < 4; ++q) {
                const int l = (m << 4) + rb + q;
                const int e = e0 + (wv << 5) + (n << 4) + col;
                part[(size_t)z * (BB * LL * DD) + (size_t)((b << 6) + l) * DD + e] = acc[m][n][q];
            }
        }
    }
}

// ---------------- K6: proj = (sum_p part) @ Wv + bv ----------------
__global__ __launch_bounds__(256) void k_proj(const float* __restrict__ part, const float* __restrict__ Wv,
                                              const float* __restrict__ bv, float* __restrict__ proj) {
    const int d0 = blockIdx.x * 64;
    const int r0 = blockIdx.y * 64;
    const int tid = threadIdx.x;
    const int rsub = (tid >> 4) << 2;
    const int dsub = (tid & 15) << 2;
    __shared__ float at[64][68];
    __shared__ float wv[64][68];
    float acc[4][4] = {{0.f, 0.f, 0.f, 0.f}};
    const size_t PSZ = (size_t)BB * LL * DD;
    for (int kc = 0; kc < 8; ++kc) {
        const int k0 = kc * 64;
        for (int k = tid; k < 1024; k += 256) {
            const int rr = k >> 4, c4 = (k & 15) << 2;
            const size_t ai = (size_t)(r0 + rr) * DD + k0 + c4;
            float4 s0 = *(const float4*)&part[ai];
            const float4 s1 = *(const float4*)&part[PSZ + ai];
            const float4 s2 = *(const float4*)&part[2 * PSZ + ai];
            const float4 s3 = *(const float4*)&part[3 * PSZ + ai];
            s0.x += s1.x + s2.x + s3.x;
            s0.y += s1.y + s2.y + s3.y;
            s0.z += s1.z + s2.z + s3.z;
            s0.w += s1.w + s2.w + s3.w;
            *(float4*)&at[rr][c4] = s0;
            *(float4*)&wv[rr][c4] = *(const float4*)&Wv[(size_t)(k0 + rr) * DD + d0 + c4];
        }
        __syncthreads();
        #pragma unroll
        for (int n4 = 0; n4 < 16; ++n4) {
            float4 a4[4];
            #pragma unroll
            for (int i = 0; i < 4; ++i) a4[i] = *(const float4*)&at[rsub + i][n4 << 2];
            const float4 b0 = *(const float4*)&wv[(n4 << 2) + 0][dsub];
            const float4 b1 = *(const float4*)&wv[(n4 << 2) + 1][dsub];
            const float4 b2 = *(const float4*)&wv[(n4 << 2) + 2][dsub];
            const float4 b3 = *(const float4*)&wv[(n4 << 2) + 3][dsub];
            #pragma unroll
            for (int i = 0; i < 4; ++i) {
                const float4 av = a4[i];
                acc[i][0] += av.x * b0.x + av.y * b1.x + av.z * b2.x + av.w * b3.x;
                acc[i][1] += av.x * b0.y + av.y * b1.y + av.z * b2.y + av.w * b3.y;
                acc[i][2] += av.x * b0.z + av.y * b1.z + av.z * b2.z + av.w * b3.z;
                acc[i][3] += av.x * b0.w + av.y * b1.w + av.z * b2.w + av.w * b3.w;
            }
        }
        __syncthreads();
    }
    #pragma unroll
    for (int i = 0; i < 4; ++i) {
        const int d = d0 + dsub;
        float4 v;
        v.x = acc[i][0] + bv[d + 0];
        v.y = acc[i][1] + bv[d + 1];
        v.z = acc[i][2] + bv[d + 2];
        v.w = acc[i][3] + bv[d + 3];
        *(float4*)&proj[(size_t)(r0 + rsub + i) * DD + d] = v;
    }
}

// ---------------- K7: RMSNorm + masks + outputs ----------------
__global__ __launch_bounds__(256) void k_rmsout(const float* __restrict__ proj, const float* __restrict__ norm_w,
                                                const int* __restrict__ allpad, float* __restrict__ out) {
    const int row = blockIdx.x;  // b*64 + l
    const int b = row >> 6;
    const int tid = threadIdx.x;
    __shared__ float red[256];
    const float* pr = proj + (size_t)row * DD;
    const float v0 = pr[tid], v1 = pr[tid + 256];
    red[tid] = v0 * v0 + v1 * v1;
    __syncthreads();
    for (int st = 128; st > 0; st >>= 1) {
        if (tid < st) red[tid] += red[tid + st];
        __syncthreads();
    }
    const float var = red[0] / (float)DD;
    const float r = 1.0f / sqrtf(var + RMS_EPS);
    const int ap = allpad[b];
    const float msk = ap ? 0.f : 1.f;
    out[(size_t)row * DD + tid]       = v0 * r * norm_w[tid] * msk;
    out[(size_t)row * DD + tid + 256] = v1 * r * norm_w[tid + 256] * msk;
    if (tid == 0) out[(size_t)BB * LL * DD + row] = ap ? 1.f : 0.f;
}

extern "C" void kernel_launch(void* const* d_in, const int* in_sizes, int n_in,
                              void* d_out, int out_size, void* d_ws, size_t ws_size,
                              hipStream_t stream) {
    const float* query   = (const float*)d_in[0];
    const float* tokens  = (const float*)d_in[1];
    const int*   pmask   = (const int*)d_in[2];
    const float* latents = (const float*)d_in[3];
    const float* Wq = (const float*)d_in[4];
    const float* bq = (const float*)d_in[5];
    const float* Wk = (const float*)d_in[6];
    const float* bk = (const float*)d_in[7];
    const float* Wv = (const float*)d_in[8];
    const float* bv = (const float*)d_in[9];
    const float* nw = (const float*)d_in[10];

    float* ws = (float*)d_ws;
    int*   allpad = (int*)ws;                 // 64 floats reserved
    float* qproj  = ws + 64;                  // 8192
    float* Lk     = ws + 8256;                // 32768
    float* Qk     = ws + 41024;               // 8192
    float* sbL    = ws + 49216;               // 64
    float* sbQ    = ws + 49280;               // pad to 49408
    float* scores = ws + 49408;               // 4194304 (f32 scores -> weights in place)
    float* part   = ws + 49408 + 4194304;     // 4*524288 = 2097152
    float* proj   = ws + 49408 + 4194304 + 2097152;  // 524288
    float* out    = (float*)d_out;

    k_allpad<<<16, 256, 0, stream>>>(pmask, allpad);
    k_qproj<<<dim3(8, 16), 256, 0, stream>>>(query, Wq, bq, qproj);
    k_lkqk<<<dim3(8, 80), 256, 0, stream>>>(latents, qproj, Wk, bk, Lk, Qk, sbL, sbQ);
    k_scores_mfma<<<dim3(32, 16), 256, 0, stream>>>(tokens, Lk, Qk, sbL, sbQ, scores);
    k_softmax<<<1024, 256, 0, stream>>>(pmask, allpad, scores);
    k_pool_mfma<<<dim3(4, 16, 4), 256, 0, stream>>>(tokens, scores, part);
    k_proj<<<dim3(8, 16), 256, 0, stream>>>(part, Wv, bv, proj);
    k_rmsout<<<1024, 256, 0, stream>>>(proj, nw, allpad, out);
}

// Round 4
// 133.020 us; speedup vs baseline: 2.5012x; 1.2241x over previous
//
#include <hip/hip_runtime.h>
#include <hip/hip_bf16.h>
#include <math.h>

#define BB 16
#define NN_ 4096
#define DD 512
#define LL 64
#define SCALE 0.044194173824159216f
#define RMS_EPS 1e-6f
#define MASKVAL -3.0e38f
#define PSZ (BB * LL * DD)   // 524288

using bf16x8 = __attribute__((ext_vector_type(8))) short;
using f32x4  = __attribute__((ext_vector_type(4))) float;

__device__ __forceinline__ unsigned short f2bf(float x) {
    return __bfloat16_as_ushort(__float2bfloat16(x));
}

// ---------------- K1: qproj = query @ Wq + bq ----------------
__global__ __launch_bounds__(256) void k_qproj(const float* __restrict__ query, const float* __restrict__ Wq,
                                               const float* __restrict__ bq, float* __restrict__ qproj) {
    const int b = blockIdx.y;
    const int dl = threadIdx.x & 63;
    const int d = (blockIdx.x << 6) + dl;
    const int wv = threadIdx.x >> 6;
    __shared__ float q[DD];
    __shared__ float red[4][64];
    for (int e = threadIdx.x; e < DD; e += 256) q[e] = query[b * DD + e];
    __syncthreads();
    float acc = 0.f;
    #pragma unroll 8
    for (int i = 0; i < 128; ++i) {
        const int e = (wv << 7) + i;
        acc += q[e] * Wq[(size_t)e * DD + d];
    }
    red[wv][dl] = acc;
    __syncthreads();
    if (threadIdx.x < 64) {
        const int dd = (blockIdx.x << 6) + threadIdx.x;
        qproj[(size_t)b * DD + dd] = red[0][threadIdx.x] + red[1][threadIdx.x] +
                                     red[2][threadIdx.x] + red[3][threadIdx.x] + bq[dd];
    }
}

// ---------------- K2: Lk/Qk = rows @ Wk^T, sbL/sbQ = rows . bk ----------------
__global__ __launch_bounds__(256) void k_lkqk(const float* __restrict__ latents, const float* __restrict__ qproj,
                                              const float* __restrict__ Wk, const float* __restrict__ bk,
                                              float* __restrict__ Lk, float* __restrict__ Qk,
                                              float* __restrict__ sbL, float* __restrict__ sbQ) {
    const int r = blockIdx.y;
    const int e0 = blockIdx.x << 6;
    const int tid = threadIdx.x;
    __shared__ float row[DD];
    const float* src = (r < LL) ? (latents + (size_t)r * DD) : (qproj + (size_t)(r - LL) * DD);
    for (int dd = tid; dd < DD; dd += 256) row[dd] = src[dd];
    __syncthreads();
    const int e = e0 + (tid >> 2);
    const int part = tid & 3;
    const float4* w4 = (const float4*)(Wk + (size_t)e * DD);
    const float4* r4 = (const float4*)row;
    float acc = 0.f;
    #pragma unroll 8
    for (int j = 0; j < 32; ++j) {
        const int d4 = part + (j << 2);
        const float4 w = w4[d4], rr = r4[d4];
        acc += w.x * rr.x + w.y * rr.y + w.z * rr.z + w.w * rr.w;
    }
    acc += __shfl_xor(acc, 1);
    acc += __shfl_xor(acc, 2);
    if (part == 0) {
        if (r < LL) Lk[(size_t)r * DD + e] = acc;
        else        Qk[(size_t)(r - LL) * DD + e] = acc;
    }
    if (blockIdx.x == 0 && tid < 64) {
        float p = 0.f;
        #pragma unroll
        for (int dd = tid; dd < DD; dd += 64) p += bk[dd] * row[dd];
        #pragma unroll
        for (int off = 32; off > 0; off >>= 1) p += __shfl_xor(p, off);
        if (tid == 0) { if (r < LL) sbL[r] = p; else sbQ[r - LL] = p; }
    }
}

// ---------------- K3: scores via MFMA bf16, 64x64 tiles, masked epilogue ----------------
// grid (64 nb, 16 b); 4 waves in 2x2; wave = 32L x 32N (acc 2x2)
__global__ __launch_bounds__(256) void k_scores_mfma(const float* __restrict__ tokens,
                                                     const float* __restrict__ Lk, const float* __restrict__ Qk,
                                                     const float* __restrict__ sbL, const float* __restrict__ sbQ,
                                                     const int* __restrict__ pmask,
                                                     float* __restrict__ scores) {
    const int b = blockIdx.y;
    const int n0 = blockIdx.x << 6;
    const int tid = threadIdx.x;
    const int lane = tid & 63, wv = tid >> 6;
    const int wl = wv >> 1, wn = wv & 1;
    __shared__ unsigned short sA[64][72];    // LQ tile [l][k]
    __shared__ unsigned short sB[64][72];    // token tile [n][k]
    f32x4 acc[2][2];
    #pragma unroll
    for (int m = 0; m < 2; ++m)
        #pragma unroll
        for (int n = 0; n < 2; ++n)
            acc[m][n] = (f32x4){0.f, 0.f, 0.f, 0.f};
    const int r = lane & 15, kl = lane >> 4;

    for (int k0 = 0; k0 < DD; k0 += 64) {
        #pragma unroll
        for (int s = 0; s < 4; ++s) {
            const int idx = tid + (s << 8);
            const int row = idx >> 4, c4 = (idx & 15) << 2;
            const float4 lv = *(const float4*)&Lk[(size_t)row * DD + k0 + c4];
            const float4 qv = *(const float4*)&Qk[(size_t)b * DD + k0 + c4];
            ushort4 o;
            o.x = f2bf(lv.x + qv.x); o.y = f2bf(lv.y + qv.y);
            o.z = f2bf(lv.z + qv.z); o.w = f2bf(lv.w + qv.w);
            *(ushort4*)&sA[row][c4] = o;
        }
        #pragma unroll
        for (int s = 0; s < 4; ++s) {
            const int idx = tid + (s << 8);
            const int row = idx >> 4, c4 = (idx & 15) << 2;
            const float4 tv = *(const float4*)&tokens[(size_t)((b << 12) + n0 + row) * DD + k0 + c4];
            ushort4 o;
            o.x = f2bf(tv.x); o.y = f2bf(tv.y); o.z = f2bf(tv.z); o.w = f2bf(tv.w);
            *(ushort4*)&sB[row][c4] = o;
        }
        __syncthreads();
        #pragma unroll
        for (int kk = 0; kk < 64; kk += 32) {
            bf16x8 af[2], bfr[2];
            #pragma unroll
            for (int m = 0; m < 2; ++m)
                af[m] = *(const bf16x8*)&sA[(wl << 5) + (m << 4) + r][kk + (kl << 3)];
            #pragma unroll
            for (int n = 0; n < 2; ++n)
                bfr[n] = *(const bf16x8*)&sB[(wn << 5) + (n << 4) + r][kk + (kl << 3)];
            #pragma unroll
            for (int m = 0; m < 2; ++m)
                #pragma unroll
                for (int n = 0; n < 2; ++n)
                    acc[m][n] = __builtin_amdgcn_mfma_f32_16x16x32_bf16(af[m], bfr[n], acc[m][n], 0, 0, 0);
        }
        __syncthreads();
    }
    const float sq = sbQ[b];
    const int col = lane & 15, rb = (lane >> 4) << 2;
    #pragma unroll
    for (int n = 0; n < 2; ++n) {
        const int ncol = n0 + (wn << 5) + (n << 4) + col;
        const int pm = pmask[(size_t)b * NN_ + ncol];
        #pragma unroll
        for (int m = 0; m < 2; ++m) {
            #pragma unroll
            for (int q = 0; q < 4; ++q) {
                const int l = (wl << 5) + (m << 4) + rb + q;
                const float sval = (acc[m][n][q] + sbL[l] + sq) * SCALE;
                scores[(size_t)((b << 6) + l) * NN_ + ncol] = pm ? MASKVAL : sval;
            }
        }
    }
}

// ---------------- K4: per-row max + 1/sum(exp) ----------------
__global__ __launch_bounds__(256) void k_denom(const float* __restrict__ scores,
                                               float* __restrict__ dm, float* __restrict__ dinv) {
    const int row = blockIdx.x;   // b*64+l
    const int tid = threadIdx.x;
    const float4* s4 = (const float4*)(scores + (size_t)row * NN_);
    float4 v[4];
    #pragma unroll
    for (int k = 0; k < 4; ++k) v[k] = ((const float4*)s4)[tid + (k << 8)];
    __shared__ float red[256];
    float mx = MASKVAL;
    #pragma unroll
    for (int k = 0; k < 4; ++k)
        mx = fmaxf(mx, fmaxf(fmaxf(v[k].x, v[k].y), fmaxf(v[k].z, v[k].w)));
    red[tid] = mx;
    __syncthreads();
    for (int st = 128; st > 0; st >>= 1) {
        if (tid < st) red[tid] = fmaxf(red[tid], red[tid + st]);
        __syncthreads();
    }
    mx = red[0];
    __syncthreads();
    float sum = 0.f;
    #pragma unroll
    for (int k = 0; k < 4; ++k)
        sum += __expf(v[k].x - mx) + __expf(v[k].y - mx) + __expf(v[k].z - mx) + __expf(v[k].w - mx);
    red[tid] = sum;
    __syncthreads();
    for (int st = 128; st > 0; st >>= 1) {
        if (tid < st) red[tid] += red[tid + st];
        __syncthreads();
    }
    if (tid == 0) { dm[row] = mx; dinv[row] = 1.f / red[0]; }
}

// ---------------- K5: pool via MFMA bf16, z=16 chunks, exp on the fly ----------------
// grid (4 eb, 16 b, 16 z); block 4 waves; wave = 64L x 32E slice (acc 4x2)
__global__ __launch_bounds__(256) void k_pool_mfma(const float* __restrict__ tokens,
                                                   const float* __restrict__ scores,
                                                   const float* __restrict__ dm, const float* __restrict__ dinv,
                                                   float* __restrict__ part) {
    const int e0 = blockIdx.x << 7;
    const int b  = blockIdx.y;
    const int z  = blockIdx.z;
    const int tid = threadIdx.x;
    const int lane = tid & 63, wv = tid >> 6;
    __shared__ unsigned short sW[64][72];    // weights tile [l][k=n]
    __shared__ int sT[128][36];              // tokens transposed [e][k-word], XOR swizzled
    f32x4 acc[4][2];
    #pragma unroll
    for (int m = 0; m < 4; ++m)
        #pragma unroll
        for (int n = 0; n < 2; ++n)
            acc[m][n] = (f32x4){0.f, 0.f, 0.f, 0.f};
    const int r = lane & 15, kl = lane >> 4;

    for (int ks = 0; ks < 4; ++ks) {
        const int n0 = (z << 8) + (ks << 6);
        #pragma unroll
        for (int s = 0; s < 4; ++s) {
            const int idx = tid + (s << 8);
            const int row = idx >> 4, c4 = (idx & 15) << 2;
            const float m = dm[(b << 6) + row];
            const float iv = dinv[(b << 6) + row];
            const float4 w = *(const float4*)&scores[(size_t)((b << 6) + row) * NN_ + n0 + c4];
            ushort4 o;
            o.x = f2bf(__expf(w.x - m) * iv); o.y = f2bf(__expf(w.y - m) * iv);
            o.z = f2bf(__expf(w.z - m) * iv); o.w = f2bf(__expf(w.w - m) * iv);
            *(ushort4*)&sW[row][c4] = o;
        }
        #pragma unroll
        for (int s = 0; s < 4; ++s) {
            const int u = tid + (s << 8);       // 0..1023
            const int n2 = u >> 5;              // token pair 0..31
            const int e4 = (u & 31) << 2;       // e offset 0..124
            const float* p0 = &tokens[(size_t)((b << 12) + n0 + (n2 << 1)) * DD + e0 + e4];
            const float4 a = *(const float4*)p0;
            const float4 c = *(const float4*)(p0 + DD);
            const float* ap = (const float*)&a;
            const float* cp = (const float*)&c;
            #pragma unroll
            for (int j = 0; j < 4; ++j) {
                const int e = e4 + j;
                const int phys = n2 ^ ((((e >> 2) & 7)) << 2);
                sT[e][phys] = (int)((unsigned)f2bf(ap[j]) | ((unsigned)f2bf(cp[j]) << 16));
            }
        }
        __syncthreads();
        #pragma unroll
        for (int kk = 0; kk < 64; kk += 32) {
            bf16x8 af[4], bfr[2];
            #pragma unroll
            for (int m = 0; m < 4; ++m)
                af[m] = *(const bf16x8*)&sW[(m << 4) + r][kk + (kl << 3)];
            #pragma unroll
            for (int n = 0; n < 2; ++n) {
                const int e = (wv << 5) + (n << 4) + r;
                const int g = (kk >> 1) + (kl << 2);
                const int phys = g ^ ((((e >> 2) & 7)) << 2);
                bfr[n] = *(const bf16x8*)&sT[e][phys];
            }
            #pragma unroll
            for (int m = 0; m < 4; ++m)
                #pragma unroll
                for (int n = 0; n < 2; ++n)
                    acc[m][n] = __builtin_amdgcn_mfma_f32_16x16x32_bf16(af[m], bfr[n], acc[m][n], 0, 0, 0);
        }
        __syncthreads();
    }
    const int col = lane & 15, rb = (lane >> 4) << 2;
    #pragma unroll
    for (int m = 0; m < 4; ++m) {
        #pragma unroll
        for (int n = 0; n < 2; ++n) {
            #pragma unroll
            for (int q = 0; q < 4; ++q) {
                const int l = (m << 4) + rb + q;
                const int e = e0 + (wv << 5) + (n << 4) + col;
                part[(size_t)z * PSZ + (size_t)((b << 6) + l) * DD + e] = acc[m][n][q];
            }
        }
    }
}

// ---------------- K6: pacc = sum_z part[z] ----------------
__global__ __launch_bounds__(256) void k_redpart(const float* __restrict__ part, float* __restrict__ pacc) {
    const int i = blockIdx.x * 256 + threadIdx.x;   // float4 index, 131072 total
    const float4* p4 = (const float4*)part;
    float4 s = p4[i];
    #pragma unroll
    for (int z = 1; z < 16; ++z) {
        const float4 v = p4[(size_t)z * (PSZ / 4) + i];
        s.x += v.x; s.y += v.y; s.z += v.z; s.w += v.w;
    }
    ((float4*)pacc)[i] = s;
}

// ---------------- K7: proj = pacc @ Wv + bv ----------------
__global__ __launch_bounds__(256) void k_proj(const float* __restrict__ pacc, const float* __restrict__ Wv,
                                              const float* __restrict__ bv, float* __restrict__ proj) {
    const int d0 = blockIdx.x * 64;
    const int r0 = blockIdx.y * 64;
    const int tid = threadIdx.x;
    const int rsub = (tid >> 4) << 2;
    const int dsub = (tid & 15) << 2;
    __shared__ float at[64][68];
    __shared__ float wv[64][68];
    float acc[4][4] = {{0.f, 0.f, 0.f, 0.f}};
    for (int kc = 0; kc < 8; ++kc) {
        const int k0 = kc * 64;
        for (int k = tid; k < 1024; k += 256) {
            const int rr = k >> 4, c4 = (k & 15) << 2;
            *(float4*)&at[rr][c4] = *(const float4*)&pacc[(size_t)(r0 + rr) * DD + k0 + c4];
            *(float4*)&wv[rr][c4] = *(const float4*)&Wv[(size_t)(k0 + rr) * DD + d0 + c4];
        }
        __syncthreads();
        #pragma unroll
        for (int n4 = 0; n4 < 16; ++n4) {
            float4 a4[4];
            #pragma unroll
            for (int i = 0; i < 4; ++i) a4[i] = *(const float4*)&at[rsub + i][n4 << 2];
            const float4 b0 = *(const float4*)&wv[(n4 << 2) + 0][dsub];
            const float4 b1 = *(const float4*)&wv[(n4 << 2) + 1][dsub];
            const float4 b2 = *(const float4*)&wv[(n4 << 2) + 2][dsub];
            const float4 b3 = *(const float4*)&wv[(n4 << 2) + 3][dsub];
            #pragma unroll
            for (int i = 0; i < 4; ++i) {
                const float4 av = a4[i];
                acc[i][0] += av.x * b0.x + av.y * b1.x + av.z * b2.x + av.w * b3.x;
                acc[i][1] += av.x * b0.y + av.y * b1.y + av.z * b2.y + av.w * b3.y;
                acc[i][2] += av.x * b0.z + av.y * b1.z + av.z * b2.z + av.w * b3.z;
                acc[i][3] += av.x * b0.w + av.y * b1.w + av.z * b2.w + av.w * b3.w;
            }
        }
        __syncthreads();
    }
    #pragma unroll
    for (int i = 0; i < 4; ++i) {
        const int d = d0 + dsub;
        float4 v;
        v.x = acc[i][0] + bv[d + 0];
        v.y = acc[i][1] + bv[d + 1];
        v.z = acc[i][2] + bv[d + 2];
        v.w = acc[i][3] + bv[d + 3];
        *(float4*)&proj[(size_t)(r0 + rsub + i) * DD + d] = v;
    }
}

// ---------------- K8: RMSNorm + masks + outputs ----------------
__global__ __launch_bounds__(256) void k_rmsout(const float* __restrict__ proj, const float* __restrict__ norm_w,
                                                const float* __restrict__ dm, float* __restrict__ out) {
    const int row = blockIdx.x;  // b*64 + l
    const int b = row >> 6;
    const int tid = threadIdx.x;
    __shared__ float red[256];
    const float* pr = proj + (size_t)row * DD;
    const float v0 = pr[tid], v1 = pr[tid + 256];
    red[tid] = v0 * v0 + v1 * v1;
    __syncthreads();
    for (int st = 128; st > 0; st >>= 1) {
        if (tid < st) red[tid] += red[tid + st];
        __syncthreads();
    }
    const float var = red[0] / (float)DD;
    const float r = 1.0f / sqrtf(var + RMS_EPS);
    const int ap = (dm[b << 6] < -1.0e38f) ? 1 : 0;   // batch all-padded iff row max is sentinel
    const float msk = ap ? 0.f : 1.f;
    out[(size_t)row * DD + tid]       = v0 * r * norm_w[tid] * msk;
    out[(size_t)row * DD + tid + 256] = v1 * r * norm_w[tid + 256] * msk;
    if (tid == 0) out[(size_t)PSZ + row] = ap ? 1.f : 0.f;
}

extern "C" void kernel_launch(void* const* d_in, const int* in_sizes, int n_in,
                              void* d_out, int out_size, void* d_ws, size_t ws_size,
                              hipStream_t stream) {
    const float* query   = (const float*)d_in[0];
    const float* tokens  = (const float*)d_in[1];
    const int*   pmask   = (const int*)d_in[2];
    const float* latents = (const float*)d_in[3];
    const float* Wq = (const float*)d_in[4];
    const float* bq = (const float*)d_in[5];
    const float* Wk = (const float*)d_in[6];
    const float* bk = (const float*)d_in[7];
    const float* Wv = (const float*)d_in[8];
    const float* bv = (const float*)d_in[9];
    const float* nw = (const float*)d_in[10];

    float* ws = (float*)d_ws;
    float* dm     = ws;                        // 1024
    float* dinv   = ws + 1024;                 // 1024
    float* qproj  = ws + 2048;                 // 8192
    float* Lk     = ws + 10240;                // 32768
    float* Qk     = ws + 43008;                // 8192
    float* sbL    = ws + 51200;                // 64
    float* sbQ    = ws + 51264;                // pad to 51456
    float* scores = ws + 51456;                // 4194304
    float* part   = ws + 51456 + 4194304;      // 16*524288 = 8388608
    float* pacc   = ws + 51456 + 4194304 + 8388608;            // 524288
    float* proj   = ws + 51456 + 4194304 + 8388608 + 524288;   // 524288
    float* out    = (float*)d_out;

    k_qproj<<<dim3(8, 16), 256, 0, stream>>>(query, Wq, bq, qproj);
    k_lkqk<<<dim3(8, 80), 256, 0, stream>>>(latents, qproj, Wk, bk, Lk, Qk, sbL, sbQ);
    k_scores_mfma<<<dim3(64, 16), 256, 0, stream>>>(tokens, Lk, Qk, sbL, sbQ, pmask, scores);
    k_denom<<<1024, 256, 0, stream>>>(scores, dm, dinv);
    k_pool_mfma<<<dim3(4, 16, 16), 256, 0, stream>>>(tokens, scores, dm, dinv, part);
    k_redpart<<<512, 256, 0, stream>>>(part, pacc);
    k_proj<<<dim3(8, 16), 256, 0, stream>>>(pacc, Wv, bv, proj);
    k_rmsout<<<1024, 256, 0, stream>>>(proj, nw, dm, out);
}

// Round 5
// 105.037 us; speedup vs baseline: 3.1676x; 1.2664x over previous
//
#include <hip/hip_runtime.h>
#include <hip/hip_bf16.h>
#include <math.h>

#define BB 16
#define NN_ 4096
#define DD 512
#define LL 64
#define SCALE 0.044194173824159216f
#define RMS_EPS 1e-6f
#define MASKVAL -3.0e38f
#define PSZ (BB * LL * DD)   // 524288
#define ZCH 16               // N-chunks (256 tokens each)

using bf16x8 = __attribute__((ext_vector_type(8))) short;
using f32x4  = __attribute__((ext_vector_type(4))) float;

__device__ __forceinline__ unsigned short f2bf(float x) {
    return __bfloat16_as_ushort(__float2bfloat16(x));
}

// ---------------- K1: qproj = query @ Wq + bq ----------------
__global__ __launch_bounds__(256) void k_qproj(const float* __restrict__ query, const float* __restrict__ Wq,
                                               const float* __restrict__ bq, float* __restrict__ qproj) {
    const int b = blockIdx.y;
    const int dl = threadIdx.x & 63;
    const int d = (blockIdx.x << 6) + dl;
    const int wv = threadIdx.x >> 6;
    __shared__ float q[DD];
    __shared__ float red[4][64];
    for (int e = threadIdx.x; e < DD; e += 256) q[e] = query[b * DD + e];
    __syncthreads();
    float acc = 0.f;
    #pragma unroll 8
    for (int i = 0; i < 128; ++i) {
        const int e = (wv << 7) + i;
        acc += q[e] * Wq[(size_t)e * DD + d];
    }
    red[wv][dl] = acc;
    __syncthreads();
    if (threadIdx.x < 64) {
        const int dd = (blockIdx.x << 6) + threadIdx.x;
        qproj[(size_t)b * DD + dd] = red[0][threadIdx.x] + red[1][threadIdx.x] +
                                     red[2][threadIdx.x] + red[3][threadIdx.x] + bq[dd];
    }
}

// ---------------- K2: Lk/Qk = rows @ Wk^T, sbL/sbQ = rows . bk ----------------
__global__ __launch_bounds__(256) void k_lkqk(const float* __restrict__ latents, const float* __restrict__ qproj,
                                              const float* __restrict__ Wk, const float* __restrict__ bk,
                                              float* __restrict__ Lk, float* __restrict__ Qk,
                                              float* __restrict__ sbL, float* __restrict__ sbQ) {
    const int r = blockIdx.y;
    const int e0 = blockIdx.x << 6;
    const int tid = threadIdx.x;
    __shared__ float row[DD];
    const float* src = (r < LL) ? (latents + (size_t)r * DD) : (qproj + (size_t)(r - LL) * DD);
    for (int dd = tid; dd < DD; dd += 256) row[dd] = src[dd];
    __syncthreads();
    const int e = e0 + (tid >> 2);
    const int part = tid & 3;
    const float4* w4 = (const float4*)(Wk + (size_t)e * DD);
    const float4* r4 = (const float4*)row;
    float acc = 0.f;
    #pragma unroll 8
    for (int j = 0; j < 32; ++j) {
        const int d4 = part + (j << 2);
        const float4 w = w4[d4], rr = r4[d4];
        acc += w.x * rr.x + w.y * rr.y + w.z * rr.z + w.w * rr.w;
    }
    acc += __shfl_xor(acc, 1);
    acc += __shfl_xor(acc, 2);
    if (part == 0) {
        if (r < LL) Lk[(size_t)r * DD + e] = acc;
        else        Qk[(size_t)(r - LL) * DD + e] = acc;
    }
    if (blockIdx.x == 0 && tid < 64) {
        float p = 0.f;
        #pragma unroll
        for (int dd = tid; dd < DD; dd += 64) p += bk[dd] * row[dd];
        #pragma unroll
        for (int off = 32; off > 0; off >>= 1) p += __shfl_xor(p, off);
        if (tid == 0) { if (r < LL) sbL[r] = p; else sbQ[r - LL] = p; }
    }
}

// ---------------- K3: fused flash scores+softmax+pool ----------------
// grid (z=16, b=16), 512 threads (8 waves). Each block: 256 tokens, all 64 latents.
// Outputs: part[z][row][512] (PV partial wrt m_z), mz[z][row], sz[z][row].
__global__ __launch_bounds__(512, 2) void k_flash(const float* __restrict__ tokens,
                                                  const float* __restrict__ Lk, const float* __restrict__ Qk,
                                                  const float* __restrict__ sbL, const float* __restrict__ sbQ,
                                                  const int* __restrict__ pmask,
                                                  float* __restrict__ part,
                                                  float* __restrict__ mz, float* __restrict__ sz) {
    const int z = blockIdx.x, b = blockIdx.y;
    const int tid = threadIdx.x;
    const int lane = tid & 63, w = tid >> 6;
    const int r16 = lane & 15, kl = lane >> 4;

    __shared__ unsigned short sB[64][72];   // token slice [n][d'] bf16 (QK^T B)
    __shared__ int sTdn[512][36];           // transposed token pairs [d][n-word], XOR swizzled (PV B)
    __shared__ unsigned short sP[64][72];   // P bf16 [l][n] (PV A)
    __shared__ float sS[64][68];            // S f32 [l][n]
    __shared__ float smem_m[64], smem_s[64], smem_rr[64], smem_ps[64];

    // ---- register-resident LQ A-fragments (rows lq..lq+15, all 512 k) ----
    const int lq = (w & 3) << 4;        // QK^T wave l-block
    const int nq = (w >> 2) << 5;       // QK^T wave n-block
    bf16x8 afLQ[16];
    {
        const int l = lq + r16;
        #pragma unroll
        for (int f = 0; f < 16; ++f) {
            const int kb = (f << 5) + (kl << 3);
            const float4 a0 = *(const float4*)&Lk[(size_t)l * DD + kb];
            const float4 a1 = *(const float4*)&Lk[(size_t)l * DD + kb + 4];
            const float4 q0 = *(const float4*)&Qk[(size_t)b * DD + kb];
            const float4 q1 = *(const float4*)&Qk[(size_t)b * DD + kb + 4];
            bf16x8 v;
            v[0] = (short)f2bf(a0.x + q0.x); v[1] = (short)f2bf(a0.y + q0.y);
            v[2] = (short)f2bf(a0.z + q0.z); v[3] = (short)f2bf(a0.w + q0.w);
            v[4] = (short)f2bf(a1.x + q1.x); v[5] = (short)f2bf(a1.y + q1.y);
            v[6] = (short)f2bf(a1.z + q1.z); v[7] = (short)f2bf(a1.w + q1.w);
            afLQ[f] = v;
        }
    }

    // PV accumulators: wave e-block w*64; rows all 64 l
    f32x4 acc[4][4];
    #pragma unroll
    for (int m = 0; m < 4; ++m)
        #pragma unroll
        for (int ef = 0; ef < 4; ++ef)
            acc[m][ef] = (f32x4){0.f, 0.f, 0.f, 0.f};

    if (tid < 64) { smem_m[tid] = MASKVAL; smem_s[tid] = 0.f; }
    __syncthreads();

    const float sq = sbQ[b];
    const int n2 = tid >> 4;            // token pair 0..31
    const int d4 = (tid & 15) << 2;     // d offset within slice

    for (int t4 = 0; t4 < 4; ++t4) {
        const int n0 = (z << 8) + (t4 << 6);
        f32x4 accS[2];
        accS[0] = (f32x4){0.f, 0.f, 0.f, 0.f};
        accS[1] = (f32x4){0.f, 0.f, 0.f, 0.f};

        // prefetch slice 0
        float4 ra, rc;
        {
            const float* p0 = &tokens[(size_t)((b << 12) + n0 + (n2 << 1)) * DD + d4];
            ra = *(const float4*)p0; rc = *(const float4*)(p0 + DD);
        }
        #pragma unroll
        for (int s8 = 0; s8 < 8; ++s8) {
            const int d0 = s8 << 6;
            // write staged regs: sB (n-major) + sTdn (d-major transposed pairs)
            {
                ushort4 oa, oc;
                oa.x = f2bf(ra.x); oa.y = f2bf(ra.y); oa.z = f2bf(ra.z); oa.w = f2bf(ra.w);
                oc.x = f2bf(rc.x); oc.y = f2bf(rc.y); oc.z = f2bf(rc.z); oc.w = f2bf(rc.w);
                *(ushort4*)&sB[(n2 << 1)][d4] = oa;
                *(ushort4*)&sB[(n2 << 1) + 1][d4] = oc;
                const float* ap = (const float*)&ra;
                const float* cp = (const float*)&rc;
                #pragma unroll
                for (int j = 0; j < 4; ++j) {
                    const int drow = d0 + d4 + j;
                    const int phys = n2 ^ (((drow >> 2) & 7) << 2);
                    sTdn[drow][phys] = (int)((unsigned)f2bf(ap[j]) | ((unsigned)f2bf(cp[j]) << 16));
                }
            }
            __syncthreads();
            // prefetch next slice (overlaps ds_read + MFMA below)
            if (s8 < 7) {
                const float* p1 = &tokens[(size_t)((b << 12) + n0 + (n2 << 1)) * DD + ((s8 + 1) << 6) + d4];
                ra = *(const float4*)p1; rc = *(const float4*)(p1 + DD);
            }
            // QK^T on this slice
            #pragma unroll
            for (int kk2 = 0; kk2 < 2; ++kk2) {
                const int f = (s8 << 1) + kk2;
                #pragma unroll
                for (int nf = 0; nf < 2; ++nf) {
                    const bf16x8 bfr = *(const bf16x8*)&sB[nq + (nf << 4) + r16][(kk2 << 5) + (kl << 3)];
                    accS[nf] = __builtin_amdgcn_mfma_f32_16x16x32_bf16(afLQ[f], bfr, accS[nf], 0, 0, 0);
                }
            }
            __syncthreads();
        }

        // ---- S epilogue: bias + scale + mask -> sS ----
        #pragma unroll
        for (int nf = 0; nf < 2; ++nf) {
            const int ncol = nq + (nf << 4) + r16;
            const int pm = pmask[(size_t)b * NN_ + n0 + ncol];
            #pragma unroll
            for (int q = 0; q < 4; ++q) {
                const int l = lq + (kl << 2) + q;
                const float sval = (accS[nf][q] + sbL[l] + sq) * SCALE;
                sS[l][ncol] = pm ? MASKVAL : sval;
            }
        }
        __syncthreads();

        // ---- online softmax stats: 8 threads per l-row ----
        const int lrow = tid >> 3, j8 = (tid & 7) << 3;
        float4 v0 = *(const float4*)&sS[lrow][j8];
        float4 v1 = *(const float4*)&sS[lrow][j8 + 4];
        float tm = fmaxf(fmaxf(fmaxf(v0.x, v0.y), fmaxf(v0.z, v0.w)),
                         fmaxf(fmaxf(v1.x, v1.y), fmaxf(v1.z, v1.w)));
        tm = fmaxf(tm, __shfl_xor(tm, 1));
        tm = fmaxf(tm, __shfl_xor(tm, 2));
        tm = fmaxf(tm, __shfl_xor(tm, 4));
        float ex[8];
        ex[0] = __expf(v0.x - tm); ex[1] = __expf(v0.y - tm);
        ex[2] = __expf(v0.z - tm); ex[3] = __expf(v0.w - tm);
        ex[4] = __expf(v1.x - tm); ex[5] = __expf(v1.y - tm);
        ex[6] = __expf(v1.z - tm); ex[7] = __expf(v1.w - tm);
        float ts = ex[0] + ex[1] + ex[2] + ex[3] + ex[4] + ex[5] + ex[6] + ex[7];
        ts += __shfl_xor(ts, 1);
        ts += __shfl_xor(ts, 2);
        ts += __shfl_xor(ts, 4);
        if ((tid & 7) == 0) {
            const float mo = smem_m[lrow];
            const float mn = fmaxf(mo, tm);
            const float rrr = __expf(mo - mn);
            const float psc = __expf(tm - mn);
            smem_m[lrow] = mn;
            smem_s[lrow] = smem_s[lrow] * rrr + ts * psc;
            smem_rr[lrow] = rrr;
            smem_ps[lrow] = psc;
        }
        __syncthreads();

        // ---- P write (bf16) + acc rescale ----
        {
            const float psc = smem_ps[lrow];
            bf16x8 pv;
            pv[0] = (short)f2bf(ex[0] * psc); pv[1] = (short)f2bf(ex[1] * psc);
            pv[2] = (short)f2bf(ex[2] * psc); pv[3] = (short)f2bf(ex[3] * psc);
            pv[4] = (short)f2bf(ex[4] * psc); pv[5] = (short)f2bf(ex[5] * psc);
            pv[6] = (short)f2bf(ex[6] * psc); pv[7] = (short)f2bf(ex[7] * psc);
            *(bf16x8*)&sP[lrow][j8] = pv;
        }
        #pragma unroll
        for (int m = 0; m < 4; ++m) {
            #pragma unroll
            for (int q = 0; q < 4; ++q) {
                const float rrr = smem_rr[(m << 4) + (kl << 2) + q];
                #pragma unroll
                for (int ef = 0; ef < 4; ++ef) acc[m][ef][q] *= rrr;
            }
        }
        __syncthreads();

        // ---- PV: out[l][e] += P[l][n] * T[n][e] (k = n) ----
        #pragma unroll
        for (int kk = 0; kk < 2; ++kk) {
            bf16x8 pa[4];
            #pragma unroll
            for (int m = 0; m < 4; ++m)
                pa[m] = *(const bf16x8*)&sP[(m << 4) + r16][(kk << 5) + (kl << 3)];
            #pragma unroll
            for (int ef = 0; ef < 4; ++ef) {
                const int e = (w << 6) + (ef << 4) + r16;
                const int g = (kk << 4) + (kl << 2);
                const int phys = g ^ (((e >> 2) & 7) << 2);
                const bf16x8 bv = *(const bf16x8*)&sTdn[e][phys];
                #pragma unroll
                for (int m = 0; m < 4; ++m)
                    acc[m][ef] = __builtin_amdgcn_mfma_f32_16x16x32_bf16(pa[m], bv, acc[m][ef], 0, 0, 0);
            }
        }
        __syncthreads();
    }

    // ---- write partials ----
    #pragma unroll
    for (int m = 0; m < 4; ++m) {
        #pragma unroll
        for (int ef = 0; ef < 4; ++ef) {
            #pragma unroll
            for (int q = 0; q < 4; ++q) {
                const int l = (m << 4) + (kl << 2) + q;
                const int e = (w << 6) + (ef << 4) + r16;
                part[(size_t)((z << 10) + (b << 6) + l) * DD + e] = acc[m][ef][q];
            }
        }
    }
    if (tid < 64) {
        mz[(z << 10) + (b << 6) + tid] = smem_m[tid];
        sz[(z << 10) + (b << 6) + tid] = smem_s[tid];
    }
}

// ---------------- K4: combine chunks with rescale + divide ----------------
__global__ __launch_bounds__(256) void k_combine(const float* __restrict__ part,
                                                 const float* __restrict__ mz, const float* __restrict__ sz,
                                                 float* __restrict__ pacc, float* __restrict__ dmg) {
    const int row = blockIdx.x;   // b*64 + l
    const int t = threadIdx.x;
    float mv[ZCH];
    float mg = MASKVAL;
    #pragma unroll
    for (int zz = 0; zz < ZCH; ++zz) {
        mv[zz] = mz[(zz << 10) + row];
        mg = fmaxf(mg, mv[zz]);
    }
    float fz[ZCH];
    float den = 0.f;
    #pragma unroll
    for (int zz = 0; zz < ZCH; ++zz) {
        fz[zz] = __expf(mv[zz] - mg);
        den += sz[(zz << 10) + row] * fz[zz];
    }
    float a0 = 0.f, a1 = 0.f;
    #pragma unroll
    for (int zz = 0; zz < ZCH; ++zz) {
        const size_t base = (size_t)((zz << 10) + row) * DD;
        a0 += part[base + t] * fz[zz];
        a1 += part[base + t + 256] * fz[zz];
    }
    const float inv = 1.f / den;
    pacc[(size_t)row * DD + t] = a0 * inv;
    pacc[(size_t)row * DD + t + 256] = a1 * inv;
    if (t == 0) dmg[row] = mg;
}

// ---------------- K5: proj = pacc @ Wv + bv ----------------
__global__ __launch_bounds__(256) void k_proj(const float* __restrict__ pacc, const float* __restrict__ Wv,
                                              const float* __restrict__ bv, float* __restrict__ proj) {
    const int d0 = blockIdx.x * 64;
    const int r0 = blockIdx.y * 64;
    const int tid = threadIdx.x;
    const int rsub = (tid >> 4) << 2;
    const int dsub = (tid & 15) << 2;
    __shared__ float at[64][68];
    __shared__ float wv[64][68];
    float acc[4][4] = {{0.f, 0.f, 0.f, 0.f}};
    for (int kc = 0; kc < 8; ++kc) {
        const int k0 = kc * 64;
        for (int k = tid; k < 1024; k += 256) {
            const int rr = k >> 4, c4 = (k & 15) << 2;
            *(float4*)&at[rr][c4] = *(const float4*)&pacc[(size_t)(r0 + rr) * DD + k0 + c4];
            *(float4*)&wv[rr][c4] = *(const float4*)&Wv[(size_t)(k0 + rr) * DD + d0 + c4];
        }
        __syncthreads();
        #pragma unroll
        for (int n4 = 0; n4 < 16; ++n4) {
            float4 a4[4];
            #pragma unroll
            for (int i = 0; i < 4; ++i) a4[i] = *(const float4*)&at[rsub + i][n4 << 2];
            const float4 b0 = *(const float4*)&wv[(n4 << 2) + 0][dsub];
            const float4 b1 = *(const float4*)&wv[(n4 << 2) + 1][dsub];
            const float4 b2 = *(const float4*)&wv[(n4 << 2) + 2][dsub];
            const float4 b3 = *(const float4*)&wv[(n4 << 2) + 3][dsub];
            #pragma unroll
            for (int i = 0; i < 4; ++i) {
                const float4 av = a4[i];
                acc[i][0] += av.x * b0.x + av.y * b1.x + av.z * b2.x + av.w * b3.x;
                acc[i][1] += av.x * b0.y + av.y * b1.y + av.z * b2.y + av.w * b3.y;
                acc[i][2] += av.x * b0.z + av.y * b1.z + av.z * b2.z + av.w * b3.z;
                acc[i][3] += av.x * b0.w + av.y * b1.w + av.z * b2.w + av.w * b3.w;
            }
        }
        __syncthreads();
    }
    #pragma unroll
    for (int i = 0; i < 4; ++i) {
        const int d = d0 + dsub;
        float4 v;
        v.x = acc[i][0] + bv[d + 0];
        v.y = acc[i][1] + bv[d + 1];
        v.z = acc[i][2] + bv[d + 2];
        v.w = acc[i][3] + bv[d + 3];
        *(float4*)&proj[(size_t)(r0 + rsub + i) * DD + d] = v;
    }
}

// ---------------- K6: RMSNorm + masks + outputs ----------------
__global__ __launch_bounds__(256) void k_rmsout(const float* __restrict__ proj, const float* __restrict__ norm_w,
                                                const float* __restrict__ dmg, float* __restrict__ out) {
    const int row = blockIdx.x;  // b*64 + l
    const int tid = threadIdx.x;
    __shared__ float red[256];
    const float* pr = proj + (size_t)row * DD;
    const float v0 = pr[tid], v1 = pr[tid + 256];
    red[tid] = v0 * v0 + v1 * v1;
    __syncthreads();
    for (int st = 128; st > 0; st >>= 1) {
        if (tid < st) red[tid] += red[tid + st];
        __syncthreads();
    }
    const float var = red[0] / (float)DD;
    const float r = 1.0f / sqrtf(var + RMS_EPS);
    const int ap = (dmg[row] < -1.0e38f) ? 1 : 0;
    const float msk = ap ? 0.f : 1.f;
    out[(size_t)row * DD + tid]       = v0 * r * norm_w[tid] * msk;
    out[(size_t)row * DD + tid + 256] = v1 * r * norm_w[tid + 256] * msk;
    if (tid == 0) out[(size_t)PSZ + row] = ap ? 1.f : 0.f;
}

extern "C" void kernel_launch(void* const* d_in, const int* in_sizes, int n_in,
                              void* d_out, int out_size, void* d_ws, size_t ws_size,
                              hipStream_t stream) {
    const float* query   = (const float*)d_in[0];
    const float* tokens  = (const float*)d_in[1];
    const int*   pmask   = (const int*)d_in[2];
    const float* latents = (const float*)d_in[3];
    const float* Wq = (const float*)d_in[4];
    const float* bq = (const float*)d_in[5];
    const float* Wk = (const float*)d_in[6];
    const float* bk = (const float*)d_in[7];
    const float* Wv = (const float*)d_in[8];
    const float* bv = (const float*)d_in[9];
    const float* nw = (const float*)d_in[10];

    float* ws = (float*)d_ws;
    float* dmg    = ws;                       // 1024
    float* mzv    = ws + 1024;                // 16384
    float* szv    = ws + 17408;               // 16384
    float* qproj  = ws + 33792;               // 8192
    float* Lk     = ws + 41984;               // 32768
    float* Qk     = ws + 74752;               // 8192
    float* sbL    = ws + 82944;               // 64
    float* sbQ    = ws + 83008;               // 64 (pad)
    float* part   = ws + 83072;               // 16*524288 = 8388608
    float* pacc   = ws + 83072 + 8388608;     // 524288
    float* proj   = ws + 83072 + 8388608 + 524288;  // 524288
    float* out    = (float*)d_out;

    k_qproj<<<dim3(8, 16), 256, 0, stream>>>(query, Wq, bq, qproj);
    k_lkqk<<<dim3(8, 80), 256, 0, stream>>>(latents, qproj, Wk, bk, Lk, Qk, sbL, sbQ);
    k_flash<<<dim3(ZCH, 16), 512, 0, stream>>>(tokens, Lk, Qk, sbL, sbQ, pmask, part, mzv, szv);
    k_combine<<<1024, 256, 0, stream>>>(part, mzv, szv, pacc, dmg);
    k_proj<<<dim3(8, 16), 256, 0, stream>>>(pacc, Wv, bv, proj);
    k_rmsout<<<1024, 256, 0, stream>>>(proj, nw, dmg, out);
}